// Round 3
// baseline (2464.742 us; speedup 1.0000x reference)
//
#include <hip/hip_runtime.h>
#include <hip/hip_bf16.h>

#define N_NODES 100000
#define N_EDGES 3200000
#define NB_SCAN 391  // ceil(N_NODES/256)

typedef __hip_bfloat16 bf16;

__device__ __forceinline__ float b2f(bf16 v) { return __bfloat162float(v); }

__device__ __forceinline__ float bits2f(unsigned short w) {
    union { unsigned short u; bf16 b; } c;
    c.u = w;
    return __bfloat162float(c.b);
}

// runtime dtype accessors -------------------------------------------------
__device__ __forceinline__ int get_idx(const void* ei, long long pos, int is64) {
    if (is64) return (int)((const long long*)ei)[pos];
    return ((const int*)ei)[pos];
}
__device__ __forceinline__ float get_f(const void* p, long long pos, int isbf) {
    if (isbf) return b2f(((const bf16*)p)[pos]);
    return ((const float*)p)[pos];
}

// ---------------- dtype detection (1 wave) ----------------
__global__ void detect_kernel(const void* __restrict__ x,
                              const void* __restrict__ ei,
                              int* __restrict__ flags) {
    int lane = threadIdx.x;  // 64 threads
    const unsigned short* xw = (const unsigned short*)x;
    float v = bits2f(xw[2 * lane]);
    bool plaus = (v == v) && fabsf(v) > 1e-3f && fabsf(v) < 1e2f;
    unsigned long long m1 = __ballot(plaus);
    const int* iw = (const int*)ei;
    bool z = (iw[2 * lane + 1] == 0);
    unsigned long long m2 = __ballot(z);
    if (lane == 0) {
        flags[0] = (__popcll(m1) >= 32) ? 1 : 0;
        flags[1] = (__popcll(m2) == 64) ? 1 : 0;
    }
}

// ---------------- degree histogram ----------------
__global__ void deg_kernel(const void* __restrict__ ei, int* __restrict__ deg,
                           const int* __restrict__ flags) {
    int is64 = flags[1];
    int i = blockIdx.x * blockDim.x + threadIdx.x;
    int stride = gridDim.x * blockDim.x;
    for (; i < N_EDGES; i += stride) {
        atomicAdd(&deg[get_idx(ei, (long long)N_EDGES + i, is64)], 1);
    }
}

// ---------------- 3-phase exclusive scan of deg -> row_start ----------------
__global__ void scan1_kernel(const int* __restrict__ deg,
                             int* __restrict__ partial, int* __restrict__ bsum) {
    __shared__ int buf[256];
    int t = threadIdx.x;
    int g = blockIdx.x * 256 + t;
    int v = (g < N_NODES) ? deg[g] : 0;
    buf[t] = v;
    __syncthreads();
    for (int off = 1; off < 256; off <<= 1) {
        int add = (t >= off) ? buf[t - off] : 0;
        __syncthreads();
        buf[t] += add;
        __syncthreads();
    }
    if (g < N_NODES) partial[g] = buf[t] - v;  // exclusive within block
    if (t == 255) bsum[blockIdx.x] = buf[t];   // block total
}

__global__ void scan2_kernel(const int* __restrict__ bsum, int* __restrict__ boff) {
    __shared__ int buf[512];
    int t = threadIdx.x;  // 512 threads
    int v = (t < NB_SCAN) ? bsum[t] : 0;
    buf[t] = v;
    __syncthreads();
    for (int off = 1; off < 512; off <<= 1) {
        int add = (t >= off) ? buf[t - off] : 0;
        __syncthreads();
        buf[t] += add;
        __syncthreads();
    }
    if (t < NB_SCAN) boff[t] = buf[t] - v;  // exclusive
}

__global__ void scan3_kernel(const int* __restrict__ partial,
                             const int* __restrict__ boff,
                             int* __restrict__ row_start, int* __restrict__ cursor) {
    int i = blockIdx.x * blockDim.x + threadIdx.x;
    if (i < N_NODES) {
        int rs = partial[i] + boff[i >> 8];
        row_start[i] = rs;
        cursor[i] = rs;
    }
    if (i == 0) row_start[N_NODES] = N_EDGES;
}

// ---------------- CSR fill: csr_src grouped by dst ----------------
__global__ void fill_kernel(const void* __restrict__ ei, int* __restrict__ cursor,
                            int* __restrict__ csr_src,
                            const int* __restrict__ flags) {
    int is64 = flags[1];
    int i = blockIdx.x * blockDim.x + threadIdx.x;
    int stride = gridDim.x * blockDim.x;
    for (; i < N_EDGES; i += stride) {
        int s = get_idx(ei, i, is64);
        int d = get_idx(ei, (long long)N_EDGES + i, is64);
        int pos = atomicAdd(&cursor[d], 1);
        csr_src[pos] = s;
    }
}

// ---------------- layer-1: gather-aggregate + fused matmuls ----------------
// one wave per node, lane = channel (64)
// agg = mean_{s in N(n)} x[s]; h = relu(agg@W1l + b1l + x[n]@W1r)
// z[n] = h@W2l (bf16); r[n] = h@W2r + b2l (bf16)
__global__ __launch_bounds__(256) void node1_kernel(
    const void* __restrict__ x, const int* __restrict__ row_start,
    const int* __restrict__ csr_src, const void* __restrict__ W1l,
    const void* __restrict__ b1l, const void* __restrict__ W1r,
    const void* __restrict__ W2l, const void* __restrict__ b2l,
    const void* __restrict__ W2r, bf16* __restrict__ zbuf,
    bf16* __restrict__ rbuf, const int* __restrict__ flags) {
    __shared__ float sW1l[64 * 64];
    __shared__ float sW1r[64 * 64];
    __shared__ float sW2l[64 * 32];
    __shared__ float sW2r[64 * 32];

    int isbf = flags[0];
    int t = threadIdx.x;
    for (int i = t; i < 64 * 64; i += 256) {
        sW1l[i] = get_f(W1l, i, isbf);
        sW1r[i] = get_f(W1r, i, isbf);
    }
    for (int i = t; i < 64 * 32; i += 256) {
        sW2l[i] = get_f(W2l, i, isbf);
        sW2r[i] = get_f(W2r, i, isbf);
    }
    __syncthreads();

    int lane = t & 63;
    int gwid = blockIdx.x * 4 + (t >> 6);
    int nwaves = gridDim.x * 4;
    float bias1 = get_f(b1l, lane, isbf);
    float bias2 = (lane >= 32) ? get_f(b2l, lane - 32, isbf) : 0.0f;
    const float* Wp = (lane < 32) ? (sW2l + lane) : (sW2r + (lane - 32));

    for (int n = gwid; n < N_NODES; n += nwaves) {
        int start = row_start[n];
        int end = row_start[n + 1];
        float acc0 = 0.0f;
        for (int base = start; base < end; base += 64) {
            int cnt = min(64, end - base);
            int idx = (lane < cnt) ? csr_src[base + lane] : 0;
            for (int j = 0; j < cnt; j++) {
                int s = __shfl(idx, j, 64);
                acc0 += get_f(x, (long long)s * 64 + lane, isbf);
            }
        }
        float invd = 1.0f / fmaxf((float)(end - start), 1.0f);
        float aggv = acc0 * invd;
        float xv = get_f(x, (long long)n * 64 + lane, isbf);
        float acc = bias1;
#pragma unroll
        for (int j = 0; j < 64; j++) {
            float aj = __shfl(aggv, j, 64);
            float xj = __shfl(xv, j, 64);
            acc = fmaf(aj, sW1l[j * 64 + lane], acc);
            acc = fmaf(xj, sW1r[j * 64 + lane], acc);
        }
        float h = fmaxf(acc, 0.0f);

        float acc2 = 0.0f;
#pragma unroll
        for (int j = 0; j < 64; j++) {
            float hj = __shfl(h, j, 64);
            acc2 = fmaf(hj, Wp[j * 32], acc2);
        }
        if (lane < 32)
            zbuf[n * 32 + lane] = __float2bfloat16(acc2);
        else
            rbuf[n * 32 + (lane - 32)] = __float2bfloat16(acc2 + bias2);
    }
}

// ---------------- layer-2: gather z + final combine ----------------
// two nodes per wave: sub-wave of 32, lane c = channel
__global__ void node2_kernel(const int* __restrict__ row_start,
                             const int* __restrict__ csr_src,
                             const bf16* __restrict__ z,
                             const bf16* __restrict__ rbuf,
                             void* __restrict__ out,
                             const int* __restrict__ flags) {
    int isbf = flags[0];
    int t = threadIdx.x;
    int lane = t & 63;
    int c = lane & 31;
    int sub = lane >> 5;
    int gwid = (blockIdx.x * blockDim.x + t) >> 6;
    int nwaves = (gridDim.x * blockDim.x) >> 6;
    for (int p = gwid; p < N_NODES / 2; p += nwaves) {
        int n = p * 2 + sub;
        int start = row_start[n];
        int end = row_start[n + 1];
        float acc = 0.0f;
        for (int base = start; base < end; base += 32) {
            int cnt = min(32, end - base);
            int idx = (c < cnt) ? csr_src[base + c] : 0;
            for (int j = 0; j < cnt; j++) {
                int s = __shfl(idx, j, 32);
                acc += b2f(z[s * 32 + c]);
            }
        }
        float invd = 1.0f / fmaxf((float)(end - start), 1.0f);
        float val = acc * invd + b2f(rbuf[n * 32 + c]);
        if (isbf)
            ((bf16*)out)[n * 32 + c] = __float2bfloat16(val);
        else
            ((float*)out)[n * 32 + c] = val;
    }
}

extern "C" void kernel_launch(void* const* d_in, const int* in_sizes, int n_in,
                              void* d_out, int out_size, void* d_ws, size_t ws_size,
                              hipStream_t stream) {
    const void* x = d_in[0];
    const void* ei = d_in[1];  // [2, E]: src = [0,E), dst = [E,2E)
    const void* W1l = d_in[2];
    const void* b1l = d_in[3];
    const void* W1r = d_in[4];
    const void* W2l = d_in[5];
    const void* b2l = d_in[6];
    const void* W2r = d_in[7];

    // workspace layout (64B-aligned offsets), total ~27.2 MB
    char* ws = (char*)d_ws;
    int* csr_src = (int*)ws;                      // E i32     = 12.8 MB
    int* row_start = (int*)(ws + 12800000);       // N+1 i32
    int* cursor = (int*)(ws + 13200064);          // N i32
    int* deg = (int*)(ws + 13600064);             // N i32
    int* partial = (int*)(ws + 14000064);         // N i32
    int* boff = (int*)(ws + 14400064);            // 512 i32
    int* bsum = (int*)(ws + 14402112);            // 512 i32
    bf16* zbuf = (bf16*)(ws + 14404160);          // N*32 bf16 = 6.4 MB
    bf16* rbuf = (bf16*)(ws + 20804160);          // N*32 bf16 = 6.4 MB
    int* flags = (int*)(ws + 27204160);           // 2 i32

    hipMemsetAsync(deg, 0, (size_t)N_NODES * 4, stream);

    detect_kernel<<<1, 64, 0, stream>>>(x, ei, flags);
    deg_kernel<<<4096, 256, 0, stream>>>(ei, deg, flags);
    scan1_kernel<<<NB_SCAN, 256, 0, stream>>>(deg, partial, bsum);
    scan2_kernel<<<1, 512, 0, stream>>>(bsum, boff);
    scan3_kernel<<<NB_SCAN, 256, 0, stream>>>(partial, boff, row_start, cursor);
    fill_kernel<<<4096, 256, 0, stream>>>(ei, cursor, csr_src, flags);
    node1_kernel<<<8192, 256, 0, stream>>>(x, row_start, csr_src, W1l, b1l, W1r,
                                           W2l, b2l, W2r, zbuf, rbuf, flags);
    node2_kernel<<<4096, 256, 0, stream>>>(row_start, csr_src, zbuf, rbuf, d_out,
                                           flags);
}

// Round 4
// 859.471 us; speedup vs baseline: 2.8677x; 2.8677x over previous
//
#include <hip/hip_runtime.h>
#include <hip/hip_bf16.h>

#define N_NODES 100000
#define N_EDGES 3200000
#define NB_SCAN 391  // ceil(N_NODES/256)

typedef __hip_bfloat16 bf16;
typedef unsigned int uint;

__device__ __forceinline__ float b2f(bf16 v) { return __bfloat162float(v); }

__device__ __forceinline__ float bits2f(unsigned short w) {
    union { unsigned short u; bf16 b; } c;
    c.u = w;
    return __bfloat162float(c.b);
}
__device__ __forceinline__ unsigned short f2bits(float f) {
    return (unsigned short)(__float_as_uint(f) >> 16);
}
__device__ __forceinline__ float rl(float v, int l) {
    return __int_as_float(__builtin_amdgcn_readlane(__float_as_int(v), l));
}

// runtime dtype accessors -------------------------------------------------
__device__ __forceinline__ int get_idx(const void* ei, long long pos, int is64) {
    if (is64) return (int)((const long long*)ei)[pos];
    return ((const int*)ei)[pos];
}
__device__ __forceinline__ float get_f(const void* p, long long pos, int isbf) {
    if (isbf) return b2f(((const bf16*)p)[pos]);
    return ((const float*)p)[pos];
}

// ---------------- dtype detection (1 wave) ----------------
__global__ void detect_kernel(const void* __restrict__ x,
                              const void* __restrict__ ei,
                              int* __restrict__ flags) {
    int lane = threadIdx.x;  // 64 threads
    const unsigned short* xw = (const unsigned short*)x;
    float v = bits2f(xw[2 * lane]);
    bool plaus = (v == v) && fabsf(v) > 1e-3f && fabsf(v) < 1e2f;
    unsigned long long m1 = __ballot(plaus);
    const int* iw = (const int*)ei;
    bool z = (iw[2 * lane + 1] == 0);
    unsigned long long m2 = __ballot(z);
    if (lane == 0) {
        flags[0] = (__popcll(m1) >= 32) ? 1 : 0;
        flags[1] = (__popcll(m2) == 64) ? 1 : 0;
    }
}

// ---------------- degree histogram ----------------
__global__ void deg_kernel(const void* __restrict__ ei, int* __restrict__ deg,
                           const int* __restrict__ flags) {
    int is64 = flags[1];
    int i = blockIdx.x * blockDim.x + threadIdx.x;
    int stride = gridDim.x * blockDim.x;
    for (; i < N_EDGES; i += stride) {
        atomicAdd(&deg[get_idx(ei, (long long)N_EDGES + i, is64)], 1);
    }
}

// ---------------- 3-phase exclusive scan of deg -> row_start ----------------
__global__ void scan1_kernel(const int* __restrict__ deg,
                             int* __restrict__ partial, int* __restrict__ bsum) {
    __shared__ int buf[256];
    int t = threadIdx.x;
    int g = blockIdx.x * 256 + t;
    int v = (g < N_NODES) ? deg[g] : 0;
    buf[t] = v;
    __syncthreads();
    for (int off = 1; off < 256; off <<= 1) {
        int add = (t >= off) ? buf[t - off] : 0;
        __syncthreads();
        buf[t] += add;
        __syncthreads();
    }
    if (g < N_NODES) partial[g] = buf[t] - v;
    if (t == 255) bsum[blockIdx.x] = buf[t];
}

__global__ void scan2_kernel(const int* __restrict__ bsum, int* __restrict__ boff) {
    __shared__ int buf[512];
    int t = threadIdx.x;  // 512 threads
    int v = (t < NB_SCAN) ? bsum[t] : 0;
    buf[t] = v;
    __syncthreads();
    for (int off = 1; off < 512; off <<= 1) {
        int add = (t >= off) ? buf[t - off] : 0;
        __syncthreads();
        buf[t] += add;
        __syncthreads();
    }
    if (t < NB_SCAN) boff[t] = buf[t] - v;
}

__global__ void scan3_kernel(const int* __restrict__ partial,
                             const int* __restrict__ boff,
                             int* __restrict__ row_start, int* __restrict__ cursor) {
    int i = blockIdx.x * blockDim.x + threadIdx.x;
    if (i < N_NODES) {
        int rs = partial[i] + boff[i >> 8];
        row_start[i] = rs;
        cursor[i] = rs;
    }
    if (i == 0) row_start[N_NODES] = N_EDGES;
}

// ---------------- CSR fill: csr_src grouped by dst ----------------
__global__ void fill_kernel(const void* __restrict__ ei, int* __restrict__ cursor,
                            int* __restrict__ csr_src,
                            const int* __restrict__ flags) {
    int is64 = flags[1];
    int i = blockIdx.x * blockDim.x + threadIdx.x;
    int stride = gridDim.x * blockDim.x;
    for (; i < N_EDGES; i += stride) {
        int s = get_idx(ei, i, is64);
        int d = get_idx(ei, (long long)N_EDGES + i, is64);
        int pos = atomicAdd(&cursor[d], 1);
        csr_src[pos] = s;
    }
}

// ---------------- layer-1: vectorized gather + fused matmuls ----------------
// Wave handles 4 nodes per group. Gather: lane = edge_slot*8 + chunk;
// one dwordx4 load covers 8 neighbor rows (bf16, 128B rows).
__global__ __launch_bounds__(256) void node1_kernel(
    const void* __restrict__ x, const int* __restrict__ row_start,
    const int* __restrict__ csr_src, const void* __restrict__ W1l,
    const void* __restrict__ b1l, const void* __restrict__ W1r,
    const void* __restrict__ W2l, const void* __restrict__ b2l,
    const void* __restrict__ W2r, bf16* __restrict__ zbuf,
    bf16* __restrict__ rbuf, const int* __restrict__ flags) {
    __shared__ uint sW1[64 * 64];  // 16 KB: lo=W1l bits, hi=W1r bits (bf16)
    __shared__ uint sW2[64 * 32];  // 8 KB: lo=W2l bits, hi=W2r bits

    int isbf = flags[0];
    int t = threadIdx.x;
    for (int i = t; i < 64 * 64; i += 256) {
        unsigned short a, b;
        if (isbf) {
            a = ((const unsigned short*)W1l)[i];
            b = ((const unsigned short*)W1r)[i];
        } else {
            a = f2bits(((const float*)W1l)[i]);
            b = f2bits(((const float*)W1r)[i]);
        }
        sW1[i] = (uint)a | ((uint)b << 16);
    }
    for (int i = t; i < 64 * 32; i += 256) {
        unsigned short a, b;
        if (isbf) {
            a = ((const unsigned short*)W2l)[i];
            b = ((const unsigned short*)W2r)[i];
        } else {
            a = f2bits(((const float*)W2l)[i]);
            b = f2bits(((const float*)W2r)[i]);
        }
        sW2[i] = (uint)a | ((uint)b << 16);
    }
    __syncthreads();

    int lane = t & 63;
    int gw = blockIdx.x * 4 + (t >> 6);
    int nwaves = gridDim.x * 4;
    float bias1 = get_f(b1l, lane, isbf);
    float bias2 = (lane >= 32) ? get_f(b2l, lane - 32, isbf) : 0.0f;

    const uint4* xr4 = (const uint4*)x;  // bf16: row = 8 uint4
    int e8 = lane >> 3, q8 = lane & 7;   // bf16 gather geometry
    int e16 = lane >> 4, q16 = lane & 15; // fp32 gather geometry

    for (int g = gw; g < N_NODES / 4; g += nwaves) {
        float aggv[4], xvv[4];
#pragma unroll
        for (int t2 = 0; t2 < 4; t2++) {
            int n = g * 4 + t2;
            int start = row_start[n];
            int end = row_start[n + 1];
            float acc[8] = {0, 0, 0, 0, 0, 0, 0, 0};
            if (isbf) {
                for (int base = start; base < end; base += 16) {
                    int i0 = base + e8, i1 = base + 8 + e8;
                    int s0 = (i0 < end) ? csr_src[i0] : -1;
                    int s1 = (i1 < end) ? csr_src[i1] : -1;
                    uint4 v0 = {0, 0, 0, 0}, v1 = {0, 0, 0, 0};
                    if (s0 >= 0) v0 = xr4[s0 * 8 + q8];
                    if (s1 >= 0) v1 = xr4[s1 * 8 + q8];
                    acc[0] += __uint_as_float(v0.x << 16) + __uint_as_float(v1.x << 16);
                    acc[1] += __uint_as_float(v0.x & 0xffff0000u) + __uint_as_float(v1.x & 0xffff0000u);
                    acc[2] += __uint_as_float(v0.y << 16) + __uint_as_float(v1.y << 16);
                    acc[3] += __uint_as_float(v0.y & 0xffff0000u) + __uint_as_float(v1.y & 0xffff0000u);
                    acc[4] += __uint_as_float(v0.z << 16) + __uint_as_float(v1.z << 16);
                    acc[5] += __uint_as_float(v0.z & 0xffff0000u) + __uint_as_float(v1.z & 0xffff0000u);
                    acc[6] += __uint_as_float(v0.w << 16) + __uint_as_float(v1.w << 16);
                    acc[7] += __uint_as_float(v0.w & 0xffff0000u) + __uint_as_float(v1.w & 0xffff0000u);
                }
                // reduce over edge slots (bits 3..5 of lane)
#pragma unroll
                for (int m = 8; m <= 32; m <<= 1)
#pragma unroll
                    for (int k = 0; k < 8; k++) acc[k] += __shfl_xor(acc[k], m, 64);
                // redistribute: channel lane = q*8+k lives in acc[lane&7] of lane (lane>>3)
                float av = 0.0f;
#pragma unroll
                for (int k = 0; k < 8; k++) {
                    float v = __shfl(acc[k], lane >> 3, 64);
                    av = ((lane & 7) == k) ? v : av;
                }
                aggv[t2] = av;
                xvv[t2] = b2f(((const bf16*)x)[(long long)n * 64 + lane]);
            } else {
                const uint4* xf = (const uint4*)x;  // fp32: row = 16 uint4
                for (int base = start; base < end; base += 8) {
                    int i0 = base + e16, i1 = base + 4 + e16;
                    int s0 = (i0 < end) ? csr_src[i0] : -1;
                    int s1 = (i1 < end) ? csr_src[i1] : -1;
                    uint4 v0 = {0, 0, 0, 0}, v1 = {0, 0, 0, 0};
                    if (s0 >= 0) v0 = xf[s0 * 16 + q16];
                    if (s1 >= 0) v1 = xf[s1 * 16 + q16];
                    acc[0] += __uint_as_float(v0.x) + __uint_as_float(v1.x);
                    acc[1] += __uint_as_float(v0.y) + __uint_as_float(v1.y);
                    acc[2] += __uint_as_float(v0.z) + __uint_as_float(v1.z);
                    acc[3] += __uint_as_float(v0.w) + __uint_as_float(v1.w);
                }
#pragma unroll
                for (int m = 16; m <= 32; m <<= 1)
#pragma unroll
                    for (int k = 0; k < 4; k++) acc[k] += __shfl_xor(acc[k], m, 64);
                float av = 0.0f;
#pragma unroll
                for (int k = 0; k < 4; k++) {
                    float v = __shfl(acc[k], lane >> 2, 64);
                    av = ((lane & 3) == k) ? v : av;
                }
                aggv[t2] = av;
                xvv[t2] = ((const float*)x)[(long long)n * 64 + lane];
            }
            int d = row_start[n + 1] - row_start[n];
            aggv[t2] *= 1.0f / fmaxf((float)d, 1.0f);
        }

        // ---- layer-1 matmul: h = relu(agg@W1l + b1l + x@W1r), 4 nodes ----
        float h0 = bias1, h1 = bias1, h2 = bias1, h3 = bias1;
#pragma unroll
        for (int j = 0; j < 64; j++) {
            uint u = sW1[j * 64 + lane];
            float w1l = __uint_as_float(u << 16);
            float w1r = __uint_as_float(u & 0xffff0000u);
            h0 = fmaf(rl(aggv[0], j), w1l, fmaf(rl(xvv[0], j), w1r, h0));
            h1 = fmaf(rl(aggv[1], j), w1l, fmaf(rl(xvv[1], j), w1r, h1));
            h2 = fmaf(rl(aggv[2], j), w1l, fmaf(rl(xvv[2], j), w1r, h2));
            h3 = fmaf(rl(aggv[3], j), w1l, fmaf(rl(xvv[3], j), w1r, h3));
        }
        h0 = fmaxf(h0, 0.0f);
        h1 = fmaxf(h1, 0.0f);
        h2 = fmaxf(h2, 0.0f);
        h3 = fmaxf(h3, 0.0f);

        // ---- layer-2 pre-projection: lanes<32 -> z = h@W2l, lanes>=32 -> r = h@W2r+b2l
        float a0 = 0, a1 = 0, a2 = 0, a3 = 0;
        bool hiHalf = (lane >= 32);
#pragma unroll
        for (int j = 0; j < 64; j++) {
            uint u = sW2[j * 32 + (lane & 31)];
            float w2 = __uint_as_float(hiHalf ? (u & 0xffff0000u) : (u << 16));
            a0 = fmaf(rl(h0, j), w2, a0);
            a1 = fmaf(rl(h1, j), w2, a1);
            a2 = fmaf(rl(h2, j), w2, a2);
            a3 = fmaf(rl(h3, j), w2, a3);
        }
        int n0 = g * 4;
        int c = lane & 31;
        if (!hiHalf) {
            zbuf[(n0 + 0) * 32 + c] = __float2bfloat16(a0);
            zbuf[(n0 + 1) * 32 + c] = __float2bfloat16(a1);
            zbuf[(n0 + 2) * 32 + c] = __float2bfloat16(a2);
            zbuf[(n0 + 3) * 32 + c] = __float2bfloat16(a3);
        } else {
            rbuf[(n0 + 0) * 32 + c] = __float2bfloat16(a0 + bias2);
            rbuf[(n0 + 1) * 32 + c] = __float2bfloat16(a1 + bias2);
            rbuf[(n0 + 2) * 32 + c] = __float2bfloat16(a2 + bias2);
            rbuf[(n0 + 3) * 32 + c] = __float2bfloat16(a3 + bias2);
        }
    }
}

// ---------------- layer-2: vectorized gather of z + final combine ----------------
// one wave per node; lane = edge_slot*4 + chunk; 32 edges per iteration
__global__ void node2_kernel(const int* __restrict__ row_start,
                             const int* __restrict__ csr_src,
                             const bf16* __restrict__ z,
                             const bf16* __restrict__ rbuf,
                             void* __restrict__ out,
                             const int* __restrict__ flags) {
    int isbf = flags[0];
    int t = threadIdx.x;
    int lane = t & 63;
    int e = lane >> 2, q = lane & 3;
    int gw = (blockIdx.x * blockDim.x + t) >> 6;
    int nwaves = (gridDim.x * blockDim.x) >> 6;
    const uint4* zr = (const uint4*)z;  // z row (32 bf16 = 64B) = 4 uint4

    for (int n = gw; n < N_NODES; n += nwaves) {
        int start = row_start[n];
        int end = row_start[n + 1];
        float acc[8] = {0, 0, 0, 0, 0, 0, 0, 0};
        for (int base = start; base < end; base += 32) {
            int i0 = base + e, i1 = base + 16 + e;
            int s0 = (i0 < end) ? csr_src[i0] : -1;
            int s1 = (i1 < end) ? csr_src[i1] : -1;
            uint4 v0 = {0, 0, 0, 0}, v1 = {0, 0, 0, 0};
            if (s0 >= 0) v0 = zr[s0 * 4 + q];
            if (s1 >= 0) v1 = zr[s1 * 4 + q];
            acc[0] += __uint_as_float(v0.x << 16) + __uint_as_float(v1.x << 16);
            acc[1] += __uint_as_float(v0.x & 0xffff0000u) + __uint_as_float(v1.x & 0xffff0000u);
            acc[2] += __uint_as_float(v0.y << 16) + __uint_as_float(v1.y << 16);
            acc[3] += __uint_as_float(v0.y & 0xffff0000u) + __uint_as_float(v1.y & 0xffff0000u);
            acc[4] += __uint_as_float(v0.z << 16) + __uint_as_float(v1.z << 16);
            acc[5] += __uint_as_float(v0.z & 0xffff0000u) + __uint_as_float(v1.z & 0xffff0000u);
            acc[6] += __uint_as_float(v0.w << 16) + __uint_as_float(v1.w << 16);
            acc[7] += __uint_as_float(v0.w & 0xffff0000u) + __uint_as_float(v1.w & 0xffff0000u);
        }
#pragma unroll
        for (int m = 4; m <= 32; m <<= 1)
#pragma unroll
            for (int k = 0; k < 8; k++) acc[k] += __shfl_xor(acc[k], m, 64);
        // channel c = q*8+k; lane c wants acc[c&7] from lane (c>>3)
        float sv = 0.0f;
#pragma unroll
        for (int k = 0; k < 8; k++) {
            float v = __shfl(acc[k], lane >> 3, 64);
            sv = ((lane & 7) == k) ? v : sv;
        }
        if (lane < 32) {
            float invd = 1.0f / fmaxf((float)(end - start), 1.0f);
            float val = sv * invd + b2f(rbuf[n * 32 + lane]);
            if (isbf)
                ((bf16*)out)[n * 32 + lane] = __float2bfloat16(val);
            else
                ((float*)out)[n * 32 + lane] = val;
        }
    }
}

extern "C" void kernel_launch(void* const* d_in, const int* in_sizes, int n_in,
                              void* d_out, int out_size, void* d_ws, size_t ws_size,
                              hipStream_t stream) {
    const void* x = d_in[0];
    const void* ei = d_in[1];  // [2, E]: src = [0,E), dst = [E,2E)
    const void* W1l = d_in[2];
    const void* b1l = d_in[3];
    const void* W1r = d_in[4];
    const void* W2l = d_in[5];
    const void* b2l = d_in[6];
    const void* W2r = d_in[7];

    // workspace layout
    char* ws = (char*)d_ws;
    int* csr_src = (int*)ws;                      // E i32     = 12.8 MB
    int* row_start = (int*)(ws + 12800000);       // N+1 i32
    int* cursor = (int*)(ws + 13200064);          // N i32
    int* deg = (int*)(ws + 13600064);             // N i32
    int* partial = (int*)(ws + 14000064);         // N i32
    int* boff = (int*)(ws + 14400064);            // 512 i32
    int* bsum = (int*)(ws + 14402112);            // 512 i32
    bf16* zbuf = (bf16*)(ws + 14404160);          // N*32 bf16 = 6.4 MB
    bf16* rbuf = (bf16*)(ws + 20804160);          // N*32 bf16 = 6.4 MB
    int* flags = (int*)(ws + 27204160);           // 2 i32

    hipMemsetAsync(deg, 0, (size_t)N_NODES * 4, stream);

    detect_kernel<<<1, 64, 0, stream>>>(x, ei, flags);
    deg_kernel<<<4096, 256, 0, stream>>>(ei, deg, flags);
    scan1_kernel<<<NB_SCAN, 256, 0, stream>>>(deg, partial, bsum);
    scan2_kernel<<<1, 512, 0, stream>>>(bsum, boff);
    scan3_kernel<<<NB_SCAN, 256, 0, stream>>>(partial, boff, row_start, cursor);
    fill_kernel<<<4096, 256, 0, stream>>>(ei, cursor, csr_src, flags);
    node1_kernel<<<2048, 256, 0, stream>>>(x, row_start, csr_src, W1l, b1l, W1r,
                                           W2l, b2l, W2r, zbuf, rbuf, flags);
    node2_kernel<<<8192, 256, 0, stream>>>(row_start, csr_src, zbuf, rbuf, d_out,
                                           flags);
}

// Round 5
// 752.538 us; speedup vs baseline: 3.2752x; 1.1421x over previous
//
#include <hip/hip_runtime.h>
#include <hip/hip_bf16.h>

#define N_NODES 100000
#define N_EDGES 3200000
#define NB_SCAN 391  // ceil(N_NODES/256)

typedef __hip_bfloat16 bf16;
typedef unsigned int uint;
typedef __attribute__((ext_vector_type(8))) short bf16x8;
typedef __attribute__((ext_vector_type(4))) float f32x4;

__device__ __forceinline__ float b2f(bf16 v) { return __bfloat162float(v); }

__device__ __forceinline__ float bits2f(unsigned short w) {
    union { unsigned short u; bf16 b; } c;
    c.u = w;
    return __bfloat162float(c.b);
}
__device__ __forceinline__ unsigned short f2bits(float f) {  // truncate
    return (unsigned short)(__float_as_uint(f) >> 16);
}
__device__ __forceinline__ unsigned short f2bf_bits(float f) {  // RNE
    bf16 b = __float2bfloat16(f);
    unsigned short u;
    __builtin_memcpy(&u, &b, 2);
    return u;
}

// runtime dtype accessors -------------------------------------------------
__device__ __forceinline__ int get_idx(const void* ei, long long pos, int is64) {
    if (is64) return (int)((const long long*)ei)[pos];
    return ((const int*)ei)[pos];
}
__device__ __forceinline__ float get_f(const void* p, long long pos, int isbf) {
    if (isbf) return b2f(((const bf16*)p)[pos]);
    return ((const float*)p)[pos];
}

// ---------------- dtype detection (1 wave) ----------------
__global__ void detect_kernel(const void* __restrict__ x,
                              const void* __restrict__ ei,
                              int* __restrict__ flags) {
    int lane = threadIdx.x;  // 64 threads
    const unsigned short* xw = (const unsigned short*)x;
    float v = bits2f(xw[2 * lane]);
    bool plaus = (v == v) && fabsf(v) > 1e-3f && fabsf(v) < 1e2f;
    unsigned long long m1 = __ballot(plaus);
    const int* iw = (const int*)ei;
    bool z = (iw[2 * lane + 1] == 0);
    unsigned long long m2 = __ballot(z);
    if (lane == 0) {
        flags[0] = (__popcll(m1) >= 32) ? 1 : 0;
        flags[1] = (__popcll(m2) == 64) ? 1 : 0;
    }
}

// ---------------- degree histogram ----------------
__global__ void deg_kernel(const void* __restrict__ ei, int* __restrict__ deg,
                           const int* __restrict__ flags) {
    int is64 = flags[1];
    int i = blockIdx.x * blockDim.x + threadIdx.x;
    int stride = gridDim.x * blockDim.x;
    for (; i < N_EDGES; i += stride) {
        atomicAdd(&deg[get_idx(ei, (long long)N_EDGES + i, is64)], 1);
    }
}

// ---------------- 3-phase exclusive scan of deg -> row_start ----------------
__global__ void scan1_kernel(const int* __restrict__ deg,
                             int* __restrict__ partial, int* __restrict__ bsum) {
    __shared__ int buf[256];
    int t = threadIdx.x;
    int g = blockIdx.x * 256 + t;
    int v = (g < N_NODES) ? deg[g] : 0;
    buf[t] = v;
    __syncthreads();
    for (int off = 1; off < 256; off <<= 1) {
        int add = (t >= off) ? buf[t - off] : 0;
        __syncthreads();
        buf[t] += add;
        __syncthreads();
    }
    if (g < N_NODES) partial[g] = buf[t] - v;
    if (t == 255) bsum[blockIdx.x] = buf[t];
}

__global__ void scan2_kernel(const int* __restrict__ bsum, int* __restrict__ boff) {
    __shared__ int buf[512];
    int t = threadIdx.x;  // 512 threads
    int v = (t < NB_SCAN) ? bsum[t] : 0;
    buf[t] = v;
    __syncthreads();
    for (int off = 1; off < 512; off <<= 1) {
        int add = (t >= off) ? buf[t - off] : 0;
        __syncthreads();
        buf[t] += add;
        __syncthreads();
    }
    if (t < NB_SCAN) boff[t] = buf[t] - v;
}

__global__ void scan3_kernel(const int* __restrict__ partial,
                             const int* __restrict__ boff,
                             int* __restrict__ row_start, int* __restrict__ cursor) {
    int i = blockIdx.x * blockDim.x + threadIdx.x;
    if (i < N_NODES) {
        int rs = partial[i] + boff[i >> 8];
        row_start[i] = rs;
        cursor[i] = rs;
    }
    if (i == 0) row_start[N_NODES] = N_EDGES;
}

// ---------------- CSR fill: csr_src grouped by dst ----------------
__global__ void fill_kernel(const void* __restrict__ ei, int* __restrict__ cursor,
                            int* __restrict__ csr_src,
                            const int* __restrict__ flags) {
    int is64 = flags[1];
    int i = blockIdx.x * blockDim.x + threadIdx.x;
    int stride = gridDim.x * blockDim.x;
    for (; i < N_EDGES; i += stride) {
        int s = get_idx(ei, i, is64);
        int d = get_idx(ei, (long long)N_EDGES + i, is64);
        int pos = atomicAdd(&cursor[d], 1);
        csr_src[pos] = s;
    }
}

// ---------------- layer-1: gather into LDS + MFMA matmuls ----------------
// Block = 256 thr (4 waves) handles 64 nodes.
// Phase A: wave w gathers agg for nodes 16w..16w+15 -> sA[m][0:64], x row -> sA[m][64:128]
// Phase B: GEMM1 h = relu([agg|x] @ [W1l;W1r] + b1l) via mfma 16x16x32 -> sH
// Phase C: GEMM2 [z|r] = h @ [W2l|W2r] (+b2l on r half) -> global
__global__ __launch_bounds__(256) void node1_kernel(
    const void* __restrict__ x, const int* __restrict__ row_start,
    const int* __restrict__ csr_src, const void* __restrict__ W1l,
    const void* __restrict__ b1l, const void* __restrict__ W1r,
    const void* __restrict__ W2l, const void* __restrict__ b2l,
    const void* __restrict__ W2r, bf16* __restrict__ zbuf,
    bf16* __restrict__ rbuf, const int* __restrict__ flags) {
    // row stride 136 bf16 = 272 B (=17*16B): 16B-aligned rows, 2-way banking (free)
    __shared__ __align__(16) unsigned short sW1t[64][136];  // [n][k0..127]
    __shared__ __align__(16) unsigned short sA[64][136];    // [m][agg|x]
    __shared__ __align__(16) unsigned short sW2t[64][72];   // [n][k0..63]
    __shared__ __align__(16) unsigned short sH[64][72];     // [m][n]
    __shared__ float sB1[64];
    __shared__ float sB2[32];

    int isbf = flags[0];
    int t = threadIdx.x;

    // ---- stage weights (transposed: [n][k]), coalesced global reads ----
    for (int i = t; i < 64 * 128; i += 256) {
        int n = i & 63, k = i >> 6;
        unsigned short v;
        if (isbf)
            v = (k < 64) ? ((const unsigned short*)W1l)[k * 64 + n]
                         : ((const unsigned short*)W1r)[(k - 64) * 64 + n];
        else
            v = f2bits((k < 64) ? ((const float*)W1l)[k * 64 + n]
                                : ((const float*)W1r)[(k - 64) * 64 + n]);
        sW1t[n][k] = v;
    }
    for (int i = t; i < 64 * 64; i += 256) {
        int n = i & 63, k = i >> 6;
        unsigned short v;
        if (isbf)
            v = (n < 32) ? ((const unsigned short*)W2l)[k * 32 + n]
                         : ((const unsigned short*)W2r)[k * 32 + (n - 32)];
        else
            v = f2bits((n < 32) ? ((const float*)W2l)[k * 32 + n]
                                : ((const float*)W2r)[k * 32 + (n - 32)]);
        sW2t[n][k] = v;
    }
    if (t < 64) sB1[t] = get_f(b1l, t, isbf);
    if (t < 32) sB2[t] = get_f(b2l, t, isbf);

    int w = t >> 6, lane = t & 63;
    int mbase = w * 16;
    int n0 = blockIdx.x * 64;
    const uint4* xr4 = (const uint4*)x;
    int e8 = lane >> 3, q8 = lane & 7;    // bf16: 8 edges x 8 chunks
    int e4 = lane >> 4, q16 = lane & 15;  // fp32: 4 edges x 16 chunks

    // ---- Phase A: gather (4 indep loads/iter = 32 edges bf16 / 16 edges fp32) ----
    for (int i = 0; i < 16; i++) {
        int m = mbase + i;
        int n = n0 + m;
        float acc[8] = {0, 0, 0, 0, 0, 0, 0, 0};
        int dg = 0;
        int start = 0, end = 0;
        if (n < N_NODES) {
            start = row_start[n];
            end = row_start[n + 1];
            dg = end - start;
        }
        float av = 0.0f, xv = 0.0f;
        if (isbf) {
            for (int base = start; base < end; base += 32) {
                int i0 = base + e8, i1 = i0 + 8, i2 = i0 + 16, i3 = i0 + 24;
                int s0 = (i0 < end) ? csr_src[i0] : -1;
                int s1 = (i1 < end) ? csr_src[i1] : -1;
                int s2 = (i2 < end) ? csr_src[i2] : -1;
                int s3 = (i3 < end) ? csr_src[i3] : -1;
                uint4 v0 = {0,0,0,0}, v1 = {0,0,0,0}, v2 = {0,0,0,0}, v3 = {0,0,0,0};
                if (s0 >= 0) v0 = xr4[s0 * 8 + q8];
                if (s1 >= 0) v1 = xr4[s1 * 8 + q8];
                if (s2 >= 0) v2 = xr4[s2 * 8 + q8];
                if (s3 >= 0) v3 = xr4[s3 * 8 + q8];
                acc[0] += __uint_as_float(v0.x << 16) + __uint_as_float(v1.x << 16)
                        + __uint_as_float(v2.x << 16) + __uint_as_float(v3.x << 16);
                acc[1] += __uint_as_float(v0.x & 0xffff0000u) + __uint_as_float(v1.x & 0xffff0000u)
                        + __uint_as_float(v2.x & 0xffff0000u) + __uint_as_float(v3.x & 0xffff0000u);
                acc[2] += __uint_as_float(v0.y << 16) + __uint_as_float(v1.y << 16)
                        + __uint_as_float(v2.y << 16) + __uint_as_float(v3.y << 16);
                acc[3] += __uint_as_float(v0.y & 0xffff0000u) + __uint_as_float(v1.y & 0xffff0000u)
                        + __uint_as_float(v2.y & 0xffff0000u) + __uint_as_float(v3.y & 0xffff0000u);
                acc[4] += __uint_as_float(v0.z << 16) + __uint_as_float(v1.z << 16)
                        + __uint_as_float(v2.z << 16) + __uint_as_float(v3.z << 16);
                acc[5] += __uint_as_float(v0.z & 0xffff0000u) + __uint_as_float(v1.z & 0xffff0000u)
                        + __uint_as_float(v2.z & 0xffff0000u) + __uint_as_float(v3.z & 0xffff0000u);
                acc[6] += __uint_as_float(v0.w << 16) + __uint_as_float(v1.w << 16)
                        + __uint_as_float(v2.w << 16) + __uint_as_float(v3.w << 16);
                acc[7] += __uint_as_float(v0.w & 0xffff0000u) + __uint_as_float(v1.w & 0xffff0000u)
                        + __uint_as_float(v2.w & 0xffff0000u) + __uint_as_float(v3.w & 0xffff0000u);
            }
#pragma unroll
            for (int mm = 8; mm <= 32; mm <<= 1)
#pragma unroll
                for (int k = 0; k < 8; k++) acc[k] += __shfl_xor(acc[k], mm, 64);
#pragma unroll
            for (int k = 0; k < 8; k++) {
                float v = __shfl(acc[k], lane >> 3, 64);
                av = ((lane & 7) == k) ? v : av;
            }
            if (n < N_NODES) xv = b2f(((const bf16*)x)[(long long)n * 64 + lane]);
        } else {
            const uint4* xf = (const uint4*)x;  // fp32 row = 16 uint4
            for (int base = start; base < end; base += 16) {
                int i0 = base + e4, i1 = i0 + 4, i2 = i0 + 8, i3 = i0 + 12;
                int s0 = (i0 < end) ? csr_src[i0] : -1;
                int s1 = (i1 < end) ? csr_src[i1] : -1;
                int s2 = (i2 < end) ? csr_src[i2] : -1;
                int s3 = (i3 < end) ? csr_src[i3] : -1;
                uint4 v0 = {0,0,0,0}, v1 = {0,0,0,0}, v2 = {0,0,0,0}, v3 = {0,0,0,0};
                if (s0 >= 0) v0 = xf[s0 * 16 + q16];
                if (s1 >= 0) v1 = xf[s1 * 16 + q16];
                if (s2 >= 0) v2 = xf[s2 * 16 + q16];
                if (s3 >= 0) v3 = xf[s3 * 16 + q16];
                acc[0] += __uint_as_float(v0.x) + __uint_as_float(v1.x)
                        + __uint_as_float(v2.x) + __uint_as_float(v3.x);
                acc[1] += __uint_as_float(v0.y) + __uint_as_float(v1.y)
                        + __uint_as_float(v2.y) + __uint_as_float(v3.y);
                acc[2] += __uint_as_float(v0.z) + __uint_as_float(v1.z)
                        + __uint_as_float(v2.z) + __uint_as_float(v3.z);
                acc[3] += __uint_as_float(v0.w) + __uint_as_float(v1.w)
                        + __uint_as_float(v2.w) + __uint_as_float(v3.w);
            }
#pragma unroll
            for (int mm = 16; mm <= 32; mm <<= 1)
#pragma unroll
                for (int k = 0; k < 4; k++) acc[k] += __shfl_xor(acc[k], mm, 64);
#pragma unroll
            for (int k = 0; k < 4; k++) {
                float v = __shfl(acc[k], lane >> 2, 64);
                av = ((lane & 3) == k) ? v : av;
            }
            if (n < N_NODES) xv = ((const float*)x)[(long long)n * 64 + lane];
        }
        av *= 1.0f / fmaxf((float)dg, 1.0f);
        sA[m][lane] = f2bf_bits(av);
        sA[m][64 + lane] = f2bf_bits(xv);
    }
    __syncthreads();

    // ---- Phase B: GEMM1 (M=16/wave, N=64, K=128) ----
    int q = lane >> 4, r15 = lane & 15;
    f32x4 acc1[4] = {{0,0,0,0},{0,0,0,0},{0,0,0,0},{0,0,0,0}};
#pragma unroll
    for (int ks = 0; ks < 4; ks++) {
        bf16x8 afrag = *(const bf16x8*)&sA[mbase + r15][ks * 32 + q * 8];
#pragma unroll
        for (int nt = 0; nt < 4; nt++) {
            bf16x8 bfrag = *(const bf16x8*)&sW1t[nt * 16 + r15][ks * 32 + q * 8];
            acc1[nt] = __builtin_amdgcn_mfma_f32_16x16x32_bf16(afrag, bfrag, acc1[nt], 0, 0, 0);
        }
    }
    // epilogue: +bias, relu -> sH (C layout: col=lane&15, row=q*4+rr)
#pragma unroll
    for (int nt = 0; nt < 4; nt++) {
        int col = nt * 16 + r15;
        float bias = sB1[col];
#pragma unroll
        for (int rr = 0; rr < 4; rr++) {
            int m = mbase + q * 4 + rr;
            sH[m][col] = f2bf_bits(fmaxf(acc1[nt][rr] + bias, 0.0f));
        }
    }
    __syncthreads();

    // ---- Phase C: GEMM2 (M=16/wave, N=64, K=64) ----
    f32x4 acc2[4] = {{0,0,0,0},{0,0,0,0},{0,0,0,0},{0,0,0,0}};
#pragma unroll
    for (int ks = 0; ks < 2; ks++) {
        bf16x8 afrag = *(const bf16x8*)&sH[mbase + r15][ks * 32 + q * 8];
#pragma unroll
        for (int nt = 0; nt < 4; nt++) {
            bf16x8 bfrag = *(const bf16x8*)&sW2t[nt * 16 + r15][ks * 32 + q * 8];
            acc2[nt] = __builtin_amdgcn_mfma_f32_16x16x32_bf16(afrag, bfrag, acc2[nt], 0, 0, 0);
        }
    }
#pragma unroll
    for (int nt = 0; nt < 4; nt++) {
        int col = nt * 16 + r15;
#pragma unroll
        for (int rr = 0; rr < 4; rr++) {
            int m = mbase + q * 4 + rr;
            int n = n0 + m;
            if (n < N_NODES) {
                float v = acc2[nt][rr];
                if (col < 32)
                    zbuf[(long long)n * 32 + col] = __float2bfloat16(v);
                else
                    rbuf[(long long)n * 32 + (col - 32)] = __float2bfloat16(v + sB2[col - 32]);
            }
        }
    }
}

// ---------------- layer-2: vectorized gather of z + final combine ----------------
__global__ void node2_kernel(const int* __restrict__ row_start,
                             const int* __restrict__ csr_src,
                             const bf16* __restrict__ z,
                             const bf16* __restrict__ rbuf,
                             void* __restrict__ out,
                             const int* __restrict__ flags) {
    int isbf = flags[0];
    int t = threadIdx.x;
    int lane = t & 63;
    int e = lane >> 2, q = lane & 3;
    int gw = (blockIdx.x * blockDim.x + t) >> 6;
    int nwaves = (gridDim.x * blockDim.x) >> 6;
    const uint4* zr = (const uint4*)z;  // z row (32 bf16 = 64B) = 4 uint4

    for (int n = gw; n < N_NODES; n += nwaves) {
        int start = row_start[n];
        int end = row_start[n + 1];
        float acc[8] = {0, 0, 0, 0, 0, 0, 0, 0};
        for (int base = start; base < end; base += 32) {
            int i0 = base + e, i1 = base + 16 + e;
            int s0 = (i0 < end) ? csr_src[i0] : -1;
            int s1 = (i1 < end) ? csr_src[i1] : -1;
            uint4 v0 = {0, 0, 0, 0}, v1 = {0, 0, 0, 0};
            if (s0 >= 0) v0 = zr[s0 * 4 + q];
            if (s1 >= 0) v1 = zr[s1 * 4 + q];
            acc[0] += __uint_as_float(v0.x << 16) + __uint_as_float(v1.x << 16);
            acc[1] += __uint_as_float(v0.x & 0xffff0000u) + __uint_as_float(v1.x & 0xffff0000u);
            acc[2] += __uint_as_float(v0.y << 16) + __uint_as_float(v1.y << 16);
            acc[3] += __uint_as_float(v0.y & 0xffff0000u) + __uint_as_float(v1.y & 0xffff0000u);
            acc[4] += __uint_as_float(v0.z << 16) + __uint_as_float(v1.z << 16);
            acc[5] += __uint_as_float(v0.z & 0xffff0000u) + __uint_as_float(v1.z & 0xffff0000u);
            acc[6] += __uint_as_float(v0.w << 16) + __uint_as_float(v1.w << 16);
            acc[7] += __uint_as_float(v0.w & 0xffff0000u) + __uint_as_float(v1.w & 0xffff0000u);
        }
#pragma unroll
        for (int m = 4; m <= 32; m <<= 1)
#pragma unroll
            for (int k = 0; k < 8; k++) acc[k] += __shfl_xor(acc[k], m, 64);
        float sv = 0.0f;
#pragma unroll
        for (int k = 0; k < 8; k++) {
            float v = __shfl(acc[k], lane >> 3, 64);
            sv = ((lane & 7) == k) ? v : sv;
        }
        if (lane < 32) {
            float invd = 1.0f / fmaxf((float)(end - start), 1.0f);
            float val = sv * invd + b2f(rbuf[n * 32 + lane]);
            if (isbf)
                ((bf16*)out)[n * 32 + lane] = __float2bfloat16(val);
            else
                ((float*)out)[n * 32 + lane] = val;
        }
    }
}

extern "C" void kernel_launch(void* const* d_in, const int* in_sizes, int n_in,
                              void* d_out, int out_size, void* d_ws, size_t ws_size,
                              hipStream_t stream) {
    const void* x = d_in[0];
    const void* ei = d_in[1];  // [2, E]: src = [0,E), dst = [E,2E)
    const void* W1l = d_in[2];
    const void* b1l = d_in[3];
    const void* W1r = d_in[4];
    const void* W2l = d_in[5];
    const void* b2l = d_in[6];
    const void* W2r = d_in[7];

    // workspace layout
    char* ws = (char*)d_ws;
    int* csr_src = (int*)ws;                      // E i32     = 12.8 MB
    int* row_start = (int*)(ws + 12800000);       // N+1 i32
    int* cursor = (int*)(ws + 13200064);          // N i32
    int* deg = (int*)(ws + 13600064);             // N i32
    int* partial = (int*)(ws + 14000064);         // N i32
    int* boff = (int*)(ws + 14400064);            // 512 i32
    int* bsum = (int*)(ws + 14402112);            // 512 i32
    bf16* zbuf = (bf16*)(ws + 14404160);          // N*32 bf16 = 6.4 MB
    bf16* rbuf = (bf16*)(ws + 20804160);          // N*32 bf16 = 6.4 MB
    int* flags = (int*)(ws + 27204160);           // 2 i32

    hipMemsetAsync(deg, 0, (size_t)N_NODES * 4, stream);

    detect_kernel<<<1, 64, 0, stream>>>(x, ei, flags);
    deg_kernel<<<4096, 256, 0, stream>>>(ei, deg, flags);
    scan1_kernel<<<NB_SCAN, 256, 0, stream>>>(deg, partial, bsum);
    scan2_kernel<<<1, 512, 0, stream>>>(bsum, boff);
    scan3_kernel<<<NB_SCAN, 256, 0, stream>>>(partial, boff, row_start, cursor);
    fill_kernel<<<4096, 256, 0, stream>>>(ei, cursor, csr_src, flags);
    node1_kernel<<<1563, 256, 0, stream>>>(x, row_start, csr_src, W1l, b1l, W1r,
                                           W2l, b2l, W2r, zbuf, rbuf, flags);
    node2_kernel<<<8192, 256, 0, stream>>>(row_start, csr_src, zbuf, rbuf, d_out,
                                           flags);
}

// Round 6
// 411.409 us; speedup vs baseline: 5.9910x; 1.8292x over previous
//
#include <hip/hip_runtime.h>
#include <hip/hip_bf16.h>

#define N_NODES 100000
#define N_EDGES 3200000
#define NBKT 391      // ceil(N_NODES/256): bucket = dst>>8
#define BKT_CAP 10240 // avg 8184 edges/bucket, +23 sigma margin

typedef __hip_bfloat16 bf16;
typedef unsigned int uint;
typedef __attribute__((ext_vector_type(8))) short bf16x8;
typedef __attribute__((ext_vector_type(4))) float f32x4;

__device__ __forceinline__ float b2f(bf16 v) { return __bfloat162float(v); }

__device__ __forceinline__ float bits2f(unsigned short w) {
    union { unsigned short u; bf16 b; } c;
    c.u = w;
    return __bfloat162float(c.b);
}
__device__ __forceinline__ unsigned short f2bits(float f) {  // truncate
    return (unsigned short)(__float_as_uint(f) >> 16);
}
__device__ __forceinline__ unsigned short f2bf_bits(float f) {  // RNE
    bf16 b = __float2bfloat16(f);
    unsigned short u;
    __builtin_memcpy(&u, &b, 2);
    return u;
}

// runtime dtype accessors -------------------------------------------------
__device__ __forceinline__ int get_idx(const void* ei, long long pos, int is64) {
    if (is64) return (int)((const long long*)ei)[pos];
    return ((const int*)ei)[pos];
}
__device__ __forceinline__ float get_f(const void* p, long long pos, int isbf) {
    if (isbf) return b2f(((const bf16*)p)[pos]);
    return ((const float*)p)[pos];
}

// ---------------- dtype detection (1 wave) ----------------
__global__ void detect_kernel(const void* __restrict__ x,
                              const void* __restrict__ ei,
                              int* __restrict__ flags) {
    int lane = threadIdx.x;  // 64 threads
    const unsigned short* xw = (const unsigned short*)x;
    float v = bits2f(xw[2 * lane]);
    bool plaus = (v == v) && fabsf(v) > 1e-3f && fabsf(v) < 1e2f;
    unsigned long long m1 = __ballot(plaus);
    const int* iw = (const int*)ei;
    bool z = (iw[2 * lane + 1] == 0);
    unsigned long long m2 = __ballot(z);
    if (lane == 0) {
        flags[0] = (__popcll(m1) >= 32) ? 1 : 0;
        flags[1] = (__popcll(m2) == 64) ? 1 : 0;
    }
}

// ---------------- pass A: bucket edges by dst>>8 ----------------
// 391 blocks x 8192 edges. Packed entry: (dst&255)<<17 | src  (25 bits)
__global__ __launch_bounds__(256) void scatterA_kernel(
    const void* __restrict__ ei, int* __restrict__ bucket_cursor,
    uint* __restrict__ bucket_data, const int* __restrict__ flags) {
    __shared__ int lhist[NBKT];
    __shared__ int lbase[NBKT];
    int is64 = flags[1];
    int t = threadIdx.x;
    int chunk0 = blockIdx.x * 8192;

    for (int i = t; i < NBKT; i += 256) lhist[i] = 0;
    __syncthreads();
    // phase 1: count chunk's bucket histogram
    for (int j = 0; j < 32; j++) {
        int e = chunk0 + j * 256 + t;
        if (e < N_EDGES) {
            int d = get_idx(ei, (long long)N_EDGES + e, is64);
            atomicAdd(&lhist[d >> 8], 1);
        }
    }
    __syncthreads();
    // reserve global space per bucket (one atomic per non-empty bucket)
    for (int i = t; i < NBKT; i += 256) {
        int c = lhist[i];
        lbase[i] = c ? atomicAdd(&bucket_cursor[i], c) : 0;
        lhist[i] = 0;  // reuse as local cursor
    }
    __syncthreads();
    // phase 2: write packed entries (re-read is L2-hot)
    for (int j = 0; j < 32; j++) {
        int e = chunk0 + j * 256 + t;
        if (e < N_EDGES) {
            int s = get_idx(ei, e, is64);
            int d = get_idx(ei, (long long)N_EDGES + e, is64);
            int b = d >> 8;
            int o = lbase[b] + atomicAdd(&lhist[b], 1);
            if (o < BKT_CAP)
                bucket_data[(long long)b * BKT_CAP + o] = ((uint)(d & 255) << 17) | (uint)s;
        }
    }
}

// ---------------- scan bucket counts -> bucket base (= csr base) ----------------
__global__ void scanBuckets_kernel(const int* __restrict__ cnt,
                                   int* __restrict__ base) {
    __shared__ int buf[512];
    int t = threadIdx.x;  // 512 threads
    int v = (t < NBKT) ? cnt[t] : 0;
    buf[t] = v;
    __syncthreads();
    for (int off = 1; off < 512; off <<= 1) {
        int add = (t >= off) ? buf[t - off] : 0;
        __syncthreads();
        buf[t] += add;
        __syncthreads();
    }
    if (t < NBKT) base[t] = buf[t] - v;  // exclusive
}

// ---------------- pass B: per-bucket CSR build (exclusive write window) ----------------
__global__ __launch_bounds__(256) void csrB_kernel(
    const int* __restrict__ bucket_cnt, const int* __restrict__ bucket_base,
    const uint* __restrict__ bucket_data, int* __restrict__ csr_src,
    int* __restrict__ row_start) {
    __shared__ int lh[256];
    __shared__ int buf[256];
    int b = blockIdx.x;
    int t = threadIdx.x;
    int cnt = bucket_cnt[b];
    if (cnt > BKT_CAP) cnt = BKT_CAP;
    int base = bucket_base[b];
    const uint* bd = bucket_data + (long long)b * BKT_CAP;

    lh[t] = 0;
    __syncthreads();
    for (int i = t; i < cnt; i += 256) atomicAdd(&lh[bd[i] >> 17], 1);
    __syncthreads();
    // exclusive scan over 256 local degrees
    int v = lh[t];
    buf[t] = v;
    __syncthreads();
    for (int off = 1; off < 256; off <<= 1) {
        int add = (t >= off) ? buf[t - off] : 0;
        __syncthreads();
        buf[t] += add;
        __syncthreads();
    }
    int excl = buf[t] - v;
    int g = (b << 8) + t;
    if (g < N_NODES) row_start[g] = base + excl;
    lh[t] = excl;  // reuse as local cursor
    __syncthreads();
    for (int i = t; i < cnt; i += 256) {
        uint e = bd[i];
        int o = atomicAdd(&lh[e >> 17], 1);
        csr_src[base + o] = (int)(e & 0x1FFFFu);
    }
    if (b == 0 && t == 0) row_start[N_NODES] = N_EDGES;
}

// ---------------- layer-1: gather into LDS + MFMA matmuls ----------------
__global__ __launch_bounds__(256) void node1_kernel(
    const void* __restrict__ x, const int* __restrict__ row_start,
    const int* __restrict__ csr_src, const void* __restrict__ W1l,
    const void* __restrict__ b1l, const void* __restrict__ W1r,
    const void* __restrict__ W2l, const void* __restrict__ b2l,
    const void* __restrict__ W2r, bf16* __restrict__ zbuf,
    bf16* __restrict__ rbuf, const int* __restrict__ flags) {
    __shared__ __align__(16) unsigned short sW1t[64][136];
    __shared__ __align__(16) unsigned short sA[64][136];
    __shared__ __align__(16) unsigned short sW2t[64][72];
    __shared__ __align__(16) unsigned short sH[64][72];
    __shared__ float sB1[64];
    __shared__ float sB2[32];

    int isbf = flags[0];
    int t = threadIdx.x;

    for (int i = t; i < 64 * 128; i += 256) {
        int n = i & 63, k = i >> 6;
        unsigned short v;
        if (isbf)
            v = (k < 64) ? ((const unsigned short*)W1l)[k * 64 + n]
                         : ((const unsigned short*)W1r)[(k - 64) * 64 + n];
        else
            v = f2bits((k < 64) ? ((const float*)W1l)[k * 64 + n]
                                : ((const float*)W1r)[(k - 64) * 64 + n]);
        sW1t[n][k] = v;
    }
    for (int i = t; i < 64 * 64; i += 256) {
        int n = i & 63, k = i >> 6;
        unsigned short v;
        if (isbf)
            v = (n < 32) ? ((const unsigned short*)W2l)[k * 32 + n]
                         : ((const unsigned short*)W2r)[k * 32 + (n - 32)];
        else
            v = f2bits((n < 32) ? ((const float*)W2l)[k * 32 + n]
                                : ((const float*)W2r)[k * 32 + (n - 32)]);
        sW2t[n][k] = v;
    }
    if (t < 64) sB1[t] = get_f(b1l, t, isbf);
    if (t < 32) sB2[t] = get_f(b2l, t, isbf);

    int w = t >> 6, lane = t & 63;
    int mbase = w * 16;
    int n0 = blockIdx.x * 64;
    const uint4* xr4 = (const uint4*)x;
    int e8 = lane >> 3, q8 = lane & 7;
    int e4 = lane >> 4, q16 = lane & 15;

    for (int i = 0; i < 16; i++) {
        int m = mbase + i;
        int n = n0 + m;
        float acc[8] = {0, 0, 0, 0, 0, 0, 0, 0};
        int dg = 0;
        int start = 0, end = 0;
        if (n < N_NODES) {
            start = row_start[n];
            end = row_start[n + 1];
            dg = end - start;
        }
        float av = 0.0f, xv = 0.0f;
        if (isbf) {
            for (int base = start; base < end; base += 32) {
                int i0 = base + e8, i1 = i0 + 8, i2 = i0 + 16, i3 = i0 + 24;
                int s0 = (i0 < end) ? csr_src[i0] : -1;
                int s1 = (i1 < end) ? csr_src[i1] : -1;
                int s2 = (i2 < end) ? csr_src[i2] : -1;
                int s3 = (i3 < end) ? csr_src[i3] : -1;
                uint4 v0 = {0,0,0,0}, v1 = {0,0,0,0}, v2 = {0,0,0,0}, v3 = {0,0,0,0};
                if (s0 >= 0) v0 = xr4[s0 * 8 + q8];
                if (s1 >= 0) v1 = xr4[s1 * 8 + q8];
                if (s2 >= 0) v2 = xr4[s2 * 8 + q8];
                if (s3 >= 0) v3 = xr4[s3 * 8 + q8];
                acc[0] += __uint_as_float(v0.x << 16) + __uint_as_float(v1.x << 16)
                        + __uint_as_float(v2.x << 16) + __uint_as_float(v3.x << 16);
                acc[1] += __uint_as_float(v0.x & 0xffff0000u) + __uint_as_float(v1.x & 0xffff0000u)
                        + __uint_as_float(v2.x & 0xffff0000u) + __uint_as_float(v3.x & 0xffff0000u);
                acc[2] += __uint_as_float(v0.y << 16) + __uint_as_float(v1.y << 16)
                        + __uint_as_float(v2.y << 16) + __uint_as_float(v3.y << 16);
                acc[3] += __uint_as_float(v0.y & 0xffff0000u) + __uint_as_float(v1.y & 0xffff0000u)
                        + __uint_as_float(v2.y & 0xffff0000u) + __uint_as_float(v3.y & 0xffff0000u);
                acc[4] += __uint_as_float(v0.z << 16) + __uint_as_float(v1.z << 16)
                        + __uint_as_float(v2.z << 16) + __uint_as_float(v3.z << 16);
                acc[5] += __uint_as_float(v0.z & 0xffff0000u) + __uint_as_float(v1.z & 0xffff0000u)
                        + __uint_as_float(v2.z & 0xffff0000u) + __uint_as_float(v3.z & 0xffff0000u);
                acc[6] += __uint_as_float(v0.w << 16) + __uint_as_float(v1.w << 16)
                        + __uint_as_float(v2.w << 16) + __uint_as_float(v3.w << 16);
                acc[7] += __uint_as_float(v0.w & 0xffff0000u) + __uint_as_float(v1.w & 0xffff0000u)
                        + __uint_as_float(v2.w & 0xffff0000u) + __uint_as_float(v3.w & 0xffff0000u);
            }
#pragma unroll
            for (int mm = 8; mm <= 32; mm <<= 1)
#pragma unroll
                for (int k = 0; k < 8; k++) acc[k] += __shfl_xor(acc[k], mm, 64);
#pragma unroll
            for (int k = 0; k < 8; k++) {
                float v = __shfl(acc[k], lane >> 3, 64);
                av = ((lane & 7) == k) ? v : av;
            }
            if (n < N_NODES) xv = b2f(((const bf16*)x)[(long long)n * 64 + lane]);
        } else {
            const uint4* xf = (const uint4*)x;
            for (int base = start; base < end; base += 16) {
                int i0 = base + e4, i1 = i0 + 4, i2 = i0 + 8, i3 = i0 + 12;
                int s0 = (i0 < end) ? csr_src[i0] : -1;
                int s1 = (i1 < end) ? csr_src[i1] : -1;
                int s2 = (i2 < end) ? csr_src[i2] : -1;
                int s3 = (i3 < end) ? csr_src[i3] : -1;
                uint4 v0 = {0,0,0,0}, v1 = {0,0,0,0}, v2 = {0,0,0,0}, v3 = {0,0,0,0};
                if (s0 >= 0) v0 = xf[s0 * 16 + q16];
                if (s1 >= 0) v1 = xf[s1 * 16 + q16];
                if (s2 >= 0) v2 = xf[s2 * 16 + q16];
                if (s3 >= 0) v3 = xf[s3 * 16 + q16];
                acc[0] += __uint_as_float(v0.x) + __uint_as_float(v1.x)
                        + __uint_as_float(v2.x) + __uint_as_float(v3.x);
                acc[1] += __uint_as_float(v0.y) + __uint_as_float(v1.y)
                        + __uint_as_float(v2.y) + __uint_as_float(v3.y);
                acc[2] += __uint_as_float(v0.z) + __uint_as_float(v1.z)
                        + __uint_as_float(v2.z) + __uint_as_float(v3.z);
                acc[3] += __uint_as_float(v0.w) + __uint_as_float(v1.w)
                        + __uint_as_float(v2.w) + __uint_as_float(v3.w);
            }
#pragma unroll
            for (int mm = 16; mm <= 32; mm <<= 1)
#pragma unroll
                for (int k = 0; k < 4; k++) acc[k] += __shfl_xor(acc[k], mm, 64);
#pragma unroll
            for (int k = 0; k < 4; k++) {
                float v = __shfl(acc[k], lane >> 2, 64);
                av = ((lane & 3) == k) ? v : av;
            }
            if (n < N_NODES) xv = ((const float*)x)[(long long)n * 64 + lane];
        }
        av *= 1.0f / fmaxf((float)dg, 1.0f);
        sA[m][lane] = f2bf_bits(av);
        sA[m][64 + lane] = f2bf_bits(xv);
    }
    __syncthreads();

    int q = lane >> 4, r15 = lane & 15;
    f32x4 acc1[4] = {{0,0,0,0},{0,0,0,0},{0,0,0,0},{0,0,0,0}};
#pragma unroll
    for (int ks = 0; ks < 4; ks++) {
        bf16x8 afrag = *(const bf16x8*)&sA[mbase + r15][ks * 32 + q * 8];
#pragma unroll
        for (int nt = 0; nt < 4; nt++) {
            bf16x8 bfrag = *(const bf16x8*)&sW1t[nt * 16 + r15][ks * 32 + q * 8];
            acc1[nt] = __builtin_amdgcn_mfma_f32_16x16x32_bf16(afrag, bfrag, acc1[nt], 0, 0, 0);
        }
    }
#pragma unroll
    for (int nt = 0; nt < 4; nt++) {
        int col = nt * 16 + r15;
        float bias = sB1[col];
#pragma unroll
        for (int rr = 0; rr < 4; rr++) {
            int m = mbase + q * 4 + rr;
            sH[m][col] = f2bf_bits(fmaxf(acc1[nt][rr] + bias, 0.0f));
        }
    }
    __syncthreads();

    f32x4 acc2[4] = {{0,0,0,0},{0,0,0,0},{0,0,0,0},{0,0,0,0}};
#pragma unroll
    for (int ks = 0; ks < 2; ks++) {
        bf16x8 afrag = *(const bf16x8*)&sH[mbase + r15][ks * 32 + q * 8];
#pragma unroll
        for (int nt = 0; nt < 4; nt++) {
            bf16x8 bfrag = *(const bf16x8*)&sW2t[nt * 16 + r15][ks * 32 + q * 8];
            acc2[nt] = __builtin_amdgcn_mfma_f32_16x16x32_bf16(afrag, bfrag, acc2[nt], 0, 0, 0);
        }
    }
#pragma unroll
    for (int nt = 0; nt < 4; nt++) {
        int col = nt * 16 + r15;
#pragma unroll
        for (int rr = 0; rr < 4; rr++) {
            int m = mbase + q * 4 + rr;
            int n = n0 + m;
            if (n < N_NODES) {
                float v = acc2[nt][rr];
                if (col < 32)
                    zbuf[(long long)n * 32 + col] = __float2bfloat16(v);
                else
                    rbuf[(long long)n * 32 + (col - 32)] = __float2bfloat16(v + sB2[col - 32]);
            }
        }
    }
}

// ---------------- layer-2: vectorized gather of z + final combine ----------------
__global__ void node2_kernel(const int* __restrict__ row_start,
                             const int* __restrict__ csr_src,
                             const bf16* __restrict__ z,
                             const bf16* __restrict__ rbuf,
                             void* __restrict__ out,
                             const int* __restrict__ flags) {
    int isbf = flags[0];
    int t = threadIdx.x;
    int lane = t & 63;
    int e = lane >> 2, q = lane & 3;
    int gw = (blockIdx.x * blockDim.x + t) >> 6;
    int nwaves = (gridDim.x * blockDim.x) >> 6;
    const uint4* zr = (const uint4*)z;

    for (int n = gw; n < N_NODES; n += nwaves) {
        int start = row_start[n];
        int end = row_start[n + 1];
        float acc[8] = {0, 0, 0, 0, 0, 0, 0, 0};
        for (int base = start; base < end; base += 32) {
            int i0 = base + e, i1 = base + 16 + e;
            int s0 = (i0 < end) ? csr_src[i0] : -1;
            int s1 = (i1 < end) ? csr_src[i1] : -1;
            uint4 v0 = {0, 0, 0, 0}, v1 = {0, 0, 0, 0};
            if (s0 >= 0) v0 = zr[s0 * 4 + q];
            if (s1 >= 0) v1 = zr[s1 * 4 + q];
            acc[0] += __uint_as_float(v0.x << 16) + __uint_as_float(v1.x << 16);
            acc[1] += __uint_as_float(v0.x & 0xffff0000u) + __uint_as_float(v1.x & 0xffff0000u);
            acc[2] += __uint_as_float(v0.y << 16) + __uint_as_float(v1.y << 16);
            acc[3] += __uint_as_float(v0.y & 0xffff0000u) + __uint_as_float(v1.y & 0xffff0000u);
            acc[4] += __uint_as_float(v0.z << 16) + __uint_as_float(v1.z << 16);
            acc[5] += __uint_as_float(v0.z & 0xffff0000u) + __uint_as_float(v1.z & 0xffff0000u);
            acc[6] += __uint_as_float(v0.w << 16) + __uint_as_float(v1.w << 16);
            acc[7] += __uint_as_float(v0.w & 0xffff0000u) + __uint_as_float(v1.w & 0xffff0000u);
        }
#pragma unroll
        for (int m = 4; m <= 32; m <<= 1)
#pragma unroll
            for (int k = 0; k < 8; k++) acc[k] += __shfl_xor(acc[k], m, 64);
        float sv = 0.0f;
#pragma unroll
        for (int k = 0; k < 8; k++) {
            float v = __shfl(acc[k], lane >> 3, 64);
            sv = ((lane & 7) == k) ? v : sv;
        }
        if (lane < 32) {
            float invd = 1.0f / fmaxf((float)(end - start), 1.0f);
            float val = sv * invd + b2f(rbuf[n * 32 + lane]);
            if (isbf)
                ((bf16*)out)[n * 32 + lane] = __float2bfloat16(val);
            else
                ((float*)out)[n * 32 + lane] = val;
        }
    }
}

extern "C" void kernel_launch(void* const* d_in, const int* in_sizes, int n_in,
                              void* d_out, int out_size, void* d_ws, size_t ws_size,
                              hipStream_t stream) {
    const void* x = d_in[0];
    const void* ei = d_in[1];  // [2, E]: src = [0,E), dst = [E,2E)
    const void* W1l = d_in[2];
    const void* b1l = d_in[3];
    const void* W1r = d_in[4];
    const void* W2l = d_in[5];
    const void* b2l = d_in[6];
    const void* W2r = d_in[7];

    // workspace layout (~42 MB)
    char* ws = (char*)d_ws;
    uint* bucket_data = (uint*)ws;                    // NBKT*BKT_CAP u32 = 16.0 MB
    int* csr_src = (int*)(ws + 16015424);             // E i32 = 12.8 MB
    int* row_start = (int*)(ws + 28815424);           // N+1 i32
    int* bucket_cursor = (int*)(ws + 29215488);       // NBKT i32
    int* bucket_base = (int*)(ws + 29217088);         // NBKT i32
    bf16* zbuf = (bf16*)(ws + 29218688);              // N*32 bf16 = 6.4 MB
    bf16* rbuf = (bf16*)(ws + 35618688);              // N*32 bf16 = 6.4 MB
    int* flags = (int*)(ws + 42018688);               // 2 i32

    hipMemsetAsync(bucket_cursor, 0, NBKT * 4, stream);

    detect_kernel<<<1, 64, 0, stream>>>(x, ei, flags);
    scatterA_kernel<<<NBKT, 256, 0, stream>>>(ei, bucket_cursor, bucket_data, flags);
    scanBuckets_kernel<<<1, 512, 0, stream>>>(bucket_cursor, bucket_base);
    csrB_kernel<<<NBKT, 256, 0, stream>>>(bucket_cursor, bucket_base, bucket_data,
                                          csr_src, row_start);
    node1_kernel<<<1563, 256, 0, stream>>>(x, row_start, csr_src, W1l, b1l, W1r,
                                           W2l, b2l, W2r, zbuf, rbuf, flags);
    node2_kernel<<<8192, 256, 0, stream>>>(row_start, csr_src, zbuf, rbuf, d_out,
                                           flags);
}

// Round 7
// 376.973 us; speedup vs baseline: 6.5382x; 1.0913x over previous
//
#include <hip/hip_runtime.h>
#include <hip/hip_bf16.h>

#define N_NODES 100000
#define N_EDGES 3200000
#define NBKT 391      // ceil(N_NODES/256): bucket = dst>>8
#define BKT_CAP 10240 // avg 8184 edges/bucket, +23 sigma margin

typedef __hip_bfloat16 bf16;
typedef unsigned int uint;
typedef __attribute__((ext_vector_type(8))) short bf16x8;
typedef __attribute__((ext_vector_type(4))) float f32x4;

__device__ __forceinline__ float b2f(bf16 v) { return __bfloat162float(v); }

__device__ __forceinline__ float bits2f(unsigned short w) {
    union { unsigned short u; bf16 b; } c;
    c.u = w;
    return __bfloat162float(c.b);
}
__device__ __forceinline__ unsigned short f2bits(float f) {  // truncate
    return (unsigned short)(__float_as_uint(f) >> 16);
}
__device__ __forceinline__ unsigned short f2bf_bits(float f) {  // RNE
    bf16 b = __float2bfloat16(f);
    unsigned short u;
    __builtin_memcpy(&u, &b, 2);
    return u;
}

// runtime dtype accessors -------------------------------------------------
__device__ __forceinline__ int get_idx(const void* ei, long long pos, int is64) {
    if (is64) return (int)((const long long*)ei)[pos];
    return ((const int*)ei)[pos];
}
__device__ __forceinline__ float get_f(const void* p, long long pos, int isbf) {
    if (isbf) return b2f(((const bf16*)p)[pos]);
    return ((const float*)p)[pos];
}

// ---------------- dtype detection (1 wave) ----------------
__global__ void detect_kernel(const void* __restrict__ x,
                              const void* __restrict__ ei,
                              int* __restrict__ flags) {
    int lane = threadIdx.x;  // 64 threads
    const unsigned short* xw = (const unsigned short*)x;
    float v = bits2f(xw[2 * lane]);
    bool plaus = (v == v) && fabsf(v) > 1e-3f && fabsf(v) < 1e2f;
    unsigned long long m1 = __ballot(plaus);
    const int* iw = (const int*)ei;
    bool z = (iw[2 * lane + 1] == 0);
    unsigned long long m2 = __ballot(z);
    if (lane == 0) {
        flags[0] = (__popcll(m1) >= 32) ? 1 : 0;
        flags[1] = (__popcll(m2) == 64) ? 1 : 0;
    }
}

// ---------------- pass A: bucket edges by dst>>8 ----------------
__global__ __launch_bounds__(256) void scatterA_kernel(
    const void* __restrict__ ei, int* __restrict__ bucket_cursor,
    uint* __restrict__ bucket_data, const int* __restrict__ flags) {
    __shared__ int lhist[NBKT];
    __shared__ int lbase[NBKT];
    int is64 = flags[1];
    int t = threadIdx.x;
    int chunk0 = blockIdx.x * 8192;

    for (int i = t; i < NBKT; i += 256) lhist[i] = 0;
    __syncthreads();
    for (int j = 0; j < 32; j++) {
        int e = chunk0 + j * 256 + t;
        if (e < N_EDGES) {
            int d = get_idx(ei, (long long)N_EDGES + e, is64);
            atomicAdd(&lhist[d >> 8], 1);
        }
    }
    __syncthreads();
    for (int i = t; i < NBKT; i += 256) {
        int c = lhist[i];
        lbase[i] = c ? atomicAdd(&bucket_cursor[i], c) : 0;
        lhist[i] = 0;  // reuse as local cursor
    }
    __syncthreads();
    for (int j = 0; j < 32; j++) {
        int e = chunk0 + j * 256 + t;
        if (e < N_EDGES) {
            int s = get_idx(ei, e, is64);
            int d = get_idx(ei, (long long)N_EDGES + e, is64);
            int b = d >> 8;
            int o = lbase[b] + atomicAdd(&lhist[b], 1);
            if (o < BKT_CAP)
                bucket_data[(long long)b * BKT_CAP + o] = ((uint)(d & 255) << 17) | (uint)s;
        }
    }
}

// ---------------- scan bucket counts -> bucket base ----------------
__global__ void scanBuckets_kernel(const int* __restrict__ cnt,
                                   int* __restrict__ base) {
    __shared__ int buf[512];
    int t = threadIdx.x;  // 512 threads
    int v = (t < NBKT) ? cnt[t] : 0;
    buf[t] = v;
    __syncthreads();
    for (int off = 1; off < 512; off <<= 1) {
        int add = (t >= off) ? buf[t - off] : 0;
        __syncthreads();
        buf[t] += add;
        __syncthreads();
    }
    if (t < NBKT) base[t] = buf[t] - v;  // exclusive
}

// ---------------- pass B: per-bucket CSR build ----------------
__global__ __launch_bounds__(256) void csrB_kernel(
    const int* __restrict__ bucket_cnt, const int* __restrict__ bucket_base,
    const uint* __restrict__ bucket_data, int* __restrict__ csr_src,
    int* __restrict__ row_start) {
    __shared__ int lh[256];
    __shared__ int buf[256];
    int b = blockIdx.x;
    int t = threadIdx.x;
    int cnt = bucket_cnt[b];
    if (cnt > BKT_CAP) cnt = BKT_CAP;
    int base = bucket_base[b];
    const uint* bd = bucket_data + (long long)b * BKT_CAP;

    lh[t] = 0;
    __syncthreads();
    for (int i = t; i < cnt; i += 256) atomicAdd(&lh[bd[i] >> 17], 1);
    __syncthreads();
    int v = lh[t];
    buf[t] = v;
    __syncthreads();
    for (int off = 1; off < 256; off <<= 1) {
        int add = (t >= off) ? buf[t - off] : 0;
        __syncthreads();
        buf[t] += add;
        __syncthreads();
    }
    int excl = buf[t] - v;
    int g = (b << 8) + t;
    if (g < N_NODES) row_start[g] = base + excl;
    lh[t] = excl;  // reuse as local cursor
    __syncthreads();
    for (int i = t; i < cnt; i += 256) {
        uint e = bd[i];
        int o = atomicAdd(&lh[e >> 17], 1);
        csr_src[base + o] = (int)(e & 0x1FFFFu);
    }
    if (b == 0 && t == 0) row_start[N_NODES] = N_EDGES;
}

// ---------------- layer-1 gather (no LDS, max occupancy) ----------------
// one wave per node (grid-stride): agg = mean of x[src] rows -> aggbuf (bf16)
__global__ __launch_bounds__(256) void gather1_kernel(
    const void* __restrict__ x, const int* __restrict__ row_start,
    const int* __restrict__ csr_src, bf16* __restrict__ aggbuf,
    const int* __restrict__ flags) {
    int isbf = flags[0];
    int t = threadIdx.x;
    int lane = t & 63;
    int gw = (blockIdx.x * 256 + t) >> 6;
    int nw = (gridDim.x * 256) >> 6;
    int e8 = lane >> 3, q8 = lane & 7;    // bf16: 8 edges x 8 chunks
    int e4 = lane >> 4, q16 = lane & 15;  // fp32: 4 edges x 16 chunks
    const uint4* xr4 = (const uint4*)x;

    for (int n = gw; n < N_NODES; n += nw) {
        int start = row_start[n];
        int end = row_start[n + 1];
        int dg = end - start;
        float acc[8] = {0, 0, 0, 0, 0, 0, 0, 0};
        float av = 0.0f;
        if (isbf) {
            for (int base = start; base < end; base += 32) {
                int i0 = base + e8, i1 = i0 + 8, i2 = i0 + 16, i3 = i0 + 24;
                int s0 = (i0 < end) ? csr_src[i0] : -1;
                int s1 = (i1 < end) ? csr_src[i1] : -1;
                int s2 = (i2 < end) ? csr_src[i2] : -1;
                int s3 = (i3 < end) ? csr_src[i3] : -1;
                uint4 v0 = {0,0,0,0}, v1 = {0,0,0,0}, v2 = {0,0,0,0}, v3 = {0,0,0,0};
                if (s0 >= 0) v0 = xr4[s0 * 8 + q8];
                if (s1 >= 0) v1 = xr4[s1 * 8 + q8];
                if (s2 >= 0) v2 = xr4[s2 * 8 + q8];
                if (s3 >= 0) v3 = xr4[s3 * 8 + q8];
                acc[0] += __uint_as_float(v0.x << 16) + __uint_as_float(v1.x << 16)
                        + __uint_as_float(v2.x << 16) + __uint_as_float(v3.x << 16);
                acc[1] += __uint_as_float(v0.x & 0xffff0000u) + __uint_as_float(v1.x & 0xffff0000u)
                        + __uint_as_float(v2.x & 0xffff0000u) + __uint_as_float(v3.x & 0xffff0000u);
                acc[2] += __uint_as_float(v0.y << 16) + __uint_as_float(v1.y << 16)
                        + __uint_as_float(v2.y << 16) + __uint_as_float(v3.y << 16);
                acc[3] += __uint_as_float(v0.y & 0xffff0000u) + __uint_as_float(v1.y & 0xffff0000u)
                        + __uint_as_float(v2.y & 0xffff0000u) + __uint_as_float(v3.y & 0xffff0000u);
                acc[4] += __uint_as_float(v0.z << 16) + __uint_as_float(v1.z << 16)
                        + __uint_as_float(v2.z << 16) + __uint_as_float(v3.z << 16);
                acc[5] += __uint_as_float(v0.z & 0xffff0000u) + __uint_as_float(v1.z & 0xffff0000u)
                        + __uint_as_float(v2.z & 0xffff0000u) + __uint_as_float(v3.z & 0xffff0000u);
                acc[6] += __uint_as_float(v0.w << 16) + __uint_as_float(v1.w << 16)
                        + __uint_as_float(v2.w << 16) + __uint_as_float(v3.w << 16);
                acc[7] += __uint_as_float(v0.w & 0xffff0000u) + __uint_as_float(v1.w & 0xffff0000u)
                        + __uint_as_float(v2.w & 0xffff0000u) + __uint_as_float(v3.w & 0xffff0000u);
            }
#pragma unroll
            for (int mm = 8; mm <= 32; mm <<= 1)
#pragma unroll
                for (int k = 0; k < 8; k++) acc[k] += __shfl_xor(acc[k], mm, 64);
#pragma unroll
            for (int k = 0; k < 8; k++) {
                float v = __shfl(acc[k], lane >> 3, 64);
                av = ((lane & 7) == k) ? v : av;
            }
        } else {
            const uint4* xf = (const uint4*)x;  // fp32 row = 16 uint4
            for (int base = start; base < end; base += 16) {
                int i0 = base + e4, i1 = i0 + 4, i2 = i0 + 8, i3 = i0 + 12;
                int s0 = (i0 < end) ? csr_src[i0] : -1;
                int s1 = (i1 < end) ? csr_src[i1] : -1;
                int s2 = (i2 < end) ? csr_src[i2] : -1;
                int s3 = (i3 < end) ? csr_src[i3] : -1;
                uint4 v0 = {0,0,0,0}, v1 = {0,0,0,0}, v2 = {0,0,0,0}, v3 = {0,0,0,0};
                if (s0 >= 0) v0 = xf[s0 * 16 + q16];
                if (s1 >= 0) v1 = xf[s1 * 16 + q16];
                if (s2 >= 0) v2 = xf[s2 * 16 + q16];
                if (s3 >= 0) v3 = xf[s3 * 16 + q16];
                acc[0] += __uint_as_float(v0.x) + __uint_as_float(v1.x)
                        + __uint_as_float(v2.x) + __uint_as_float(v3.x);
                acc[1] += __uint_as_float(v0.y) + __uint_as_float(v1.y)
                        + __uint_as_float(v2.y) + __uint_as_float(v3.y);
                acc[2] += __uint_as_float(v0.z) + __uint_as_float(v1.z)
                        + __uint_as_float(v2.z) + __uint_as_float(v3.z);
                acc[3] += __uint_as_float(v0.w) + __uint_as_float(v1.w)
                        + __uint_as_float(v2.w) + __uint_as_float(v3.w);
            }
#pragma unroll
            for (int mm = 16; mm <= 32; mm <<= 1)
#pragma unroll
                for (int k = 0; k < 4; k++) acc[k] += __shfl_xor(acc[k], mm, 64);
#pragma unroll
            for (int k = 0; k < 4; k++) {
                float v = __shfl(acc[k], lane >> 2, 64);
                av = ((lane & 3) == k) ? v : av;
            }
        }
        av *= 1.0f / fmaxf((float)dg, 1.0f);
        aggbuf[(long long)n * 64 + lane] = __float2bfloat16(av);
    }
}

// ---------------- layer-1+2 GEMMs (MFMA, dense coalesced staging) ----------------
// Block = 256 thr handles 64 nodes. sA[m] = [agg(n) | x(n)] bf16.
__global__ __launch_bounds__(256) void gemm1_kernel(
    const void* __restrict__ x, const bf16* __restrict__ aggbuf,
    const void* __restrict__ W1l, const void* __restrict__ b1l,
    const void* __restrict__ W1r, const void* __restrict__ W2l,
    const void* __restrict__ b2l, const void* __restrict__ W2r,
    bf16* __restrict__ zbuf, bf16* __restrict__ rbuf,
    const int* __restrict__ flags) {
    __shared__ __align__(16) unsigned short sW1t[64][136];
    __shared__ __align__(16) unsigned short sA[64][136];
    __shared__ __align__(16) unsigned short sW2t[64][72];
    __shared__ __align__(16) unsigned short sH[64][72];
    __shared__ float sB1[64];
    __shared__ float sB2[32];

    int isbf = flags[0];
    int t = threadIdx.x;
    int n0 = blockIdx.x * 64;

    // stage weights (transposed [n][k])
    for (int i = t; i < 64 * 128; i += 256) {
        int n = i & 63, k = i >> 6;
        unsigned short v;
        if (isbf)
            v = (k < 64) ? ((const unsigned short*)W1l)[k * 64 + n]
                         : ((const unsigned short*)W1r)[(k - 64) * 64 + n];
        else
            v = f2bits((k < 64) ? ((const float*)W1l)[k * 64 + n]
                                : ((const float*)W1r)[(k - 64) * 64 + n]);
        sW1t[n][k] = v;
    }
    for (int i = t; i < 64 * 64; i += 256) {
        int n = i & 63, k = i >> 6;
        unsigned short v;
        if (isbf)
            v = (n < 32) ? ((const unsigned short*)W2l)[k * 32 + n]
                         : ((const unsigned short*)W2r)[k * 32 + (n - 32)];
        else
            v = f2bits((n < 32) ? ((const float*)W2l)[k * 32 + n]
                                : ((const float*)W2r)[k * 32 + (n - 32)]);
        sW2t[n][k] = v;
    }
    if (t < 64) sB1[t] = get_f(b1l, t, isbf);
    if (t < 32) sB2[t] = get_f(b2l, t, isbf);

    // stage A: dense coalesced loads (agg rows + x rows)
    const uint4* ag4 = (const uint4*)aggbuf;
    if (isbf) {
        const uint4* x4 = (const uint4*)x;
        for (int i = t; i < 64 * 16; i += 256) {
            int m = i >> 4, c = i & 15;
            int nn = min(n0 + m, N_NODES - 1);
            uint4 v = (c < 8) ? ag4[(long long)nn * 8 + c]
                              : x4[(long long)nn * 8 + (c - 8)];
            *(uint4*)&sA[m][c * 8] = v;
        }
    } else {
        for (int i = t; i < 64 * 8; i += 256) {
            int m = i >> 3, c = i & 7;
            int nn = min(n0 + m, N_NODES - 1);
            *(uint4*)&sA[m][c * 8] = ag4[(long long)nn * 8 + c];
        }
        const float* xf = (const float*)x;
        for (int i = t; i < 64 * 64; i += 256) {
            int m = i >> 6, c = i & 63;
            int nn = min(n0 + m, N_NODES - 1);
            sA[m][64 + c] = f2bf_bits(xf[(long long)nn * 64 + c]);
        }
    }
    __syncthreads();

    int w = t >> 6, lane = t & 63;
    int mbase = w * 16;
    int q = lane >> 4, r15 = lane & 15;
    f32x4 acc1[4] = {{0,0,0,0},{0,0,0,0},{0,0,0,0},{0,0,0,0}};
#pragma unroll
    for (int ks = 0; ks < 4; ks++) {
        bf16x8 afrag = *(const bf16x8*)&sA[mbase + r15][ks * 32 + q * 8];
#pragma unroll
        for (int nt = 0; nt < 4; nt++) {
            bf16x8 bfrag = *(const bf16x8*)&sW1t[nt * 16 + r15][ks * 32 + q * 8];
            acc1[nt] = __builtin_amdgcn_mfma_f32_16x16x32_bf16(afrag, bfrag, acc1[nt], 0, 0, 0);
        }
    }
#pragma unroll
    for (int nt = 0; nt < 4; nt++) {
        int col = nt * 16 + r15;
        float bias = sB1[col];
#pragma unroll
        for (int rr = 0; rr < 4; rr++) {
            int m = mbase + q * 4 + rr;
            sH[m][col] = f2bf_bits(fmaxf(acc1[nt][rr] + bias, 0.0f));
        }
    }
    __syncthreads();

    f32x4 acc2[4] = {{0,0,0,0},{0,0,0,0},{0,0,0,0},{0,0,0,0}};
#pragma unroll
    for (int ks = 0; ks < 2; ks++) {
        bf16x8 afrag = *(const bf16x8*)&sH[mbase + r15][ks * 32 + q * 8];
#pragma unroll
        for (int nt = 0; nt < 4; nt++) {
            bf16x8 bfrag = *(const bf16x8*)&sW2t[nt * 16 + r15][ks * 32 + q * 8];
            acc2[nt] = __builtin_amdgcn_mfma_f32_16x16x32_bf16(afrag, bfrag, acc2[nt], 0, 0, 0);
        }
    }
#pragma unroll
    for (int nt = 0; nt < 4; nt++) {
        int col = nt * 16 + r15;
#pragma unroll
        for (int rr = 0; rr < 4; rr++) {
            int m = mbase + q * 4 + rr;
            int n = n0 + m;
            if (n < N_NODES) {
                float v = acc2[nt][rr];
                if (col < 32)
                    zbuf[(long long)n * 32 + col] = __float2bfloat16(v);
                else
                    rbuf[(long long)n * 32 + (col - 32)] = __float2bfloat16(v + sB2[col - 32]);
            }
        }
    }
}

// ---------------- layer-2: vectorized gather of z + final combine ----------------
__global__ void node2_kernel(const int* __restrict__ row_start,
                             const int* __restrict__ csr_src,
                             const bf16* __restrict__ z,
                             const bf16* __restrict__ rbuf,
                             void* __restrict__ out,
                             const int* __restrict__ flags) {
    int isbf = flags[0];
    int t = threadIdx.x;
    int lane = t & 63;
    int e = lane >> 2, q = lane & 3;
    int gw = (blockIdx.x * blockDim.x + t) >> 6;
    int nwaves = (gridDim.x * blockDim.x) >> 6;
    const uint4* zr = (const uint4*)z;

    for (int n = gw; n < N_NODES; n += nwaves) {
        int start = row_start[n];
        int end = row_start[n + 1];
        float acc[8] = {0, 0, 0, 0, 0, 0, 0, 0};
        for (int base = start; base < end; base += 32) {
            int i0 = base + e, i1 = base + 16 + e;
            int s0 = (i0 < end) ? csr_src[i0] : -1;
            int s1 = (i1 < end) ? csr_src[i1] : -1;
            uint4 v0 = {0, 0, 0, 0}, v1 = {0, 0, 0, 0};
            if (s0 >= 0) v0 = zr[s0 * 4 + q];
            if (s1 >= 0) v1 = zr[s1 * 4 + q];
            acc[0] += __uint_as_float(v0.x << 16) + __uint_as_float(v1.x << 16);
            acc[1] += __uint_as_float(v0.x & 0xffff0000u) + __uint_as_float(v1.x & 0xffff0000u);
            acc[2] += __uint_as_float(v0.y << 16) + __uint_as_float(v1.y << 16);
            acc[3] += __uint_as_float(v0.y & 0xffff0000u) + __uint_as_float(v1.y & 0xffff0000u);
            acc[4] += __uint_as_float(v0.z << 16) + __uint_as_float(v1.z << 16);
            acc[5] += __uint_as_float(v0.z & 0xffff0000u) + __uint_as_float(v1.z & 0xffff0000u);
            acc[6] += __uint_as_float(v0.w << 16) + __uint_as_float(v1.w << 16);
            acc[7] += __uint_as_float(v0.w & 0xffff0000u) + __uint_as_float(v1.w & 0xffff0000u);
        }
#pragma unroll
        for (int m = 4; m <= 32; m <<= 1)
#pragma unroll
            for (int k = 0; k < 8; k++) acc[k] += __shfl_xor(acc[k], m, 64);
        float sv = 0.0f;
#pragma unroll
        for (int k = 0; k < 8; k++) {
            float v = __shfl(acc[k], lane >> 3, 64);
            sv = ((lane & 7) == k) ? v : sv;
        }
        if (lane < 32) {
            float invd = 1.0f / fmaxf((float)(end - start), 1.0f);
            float val = sv * invd + b2f(rbuf[n * 32 + lane]);
            if (isbf)
                ((bf16*)out)[n * 32 + lane] = __float2bfloat16(val);
            else
                ((float*)out)[n * 32 + lane] = val;
        }
    }
}

extern "C" void kernel_launch(void* const* d_in, const int* in_sizes, int n_in,
                              void* d_out, int out_size, void* d_ws, size_t ws_size,
                              hipStream_t stream) {
    const void* x = d_in[0];
    const void* ei = d_in[1];  // [2, E]: src = [0,E), dst = [E,2E)
    const void* W1l = d_in[2];
    const void* b1l = d_in[3];
    const void* W1r = d_in[4];
    const void* W2l = d_in[5];
    const void* b2l = d_in[6];
    const void* W2r = d_in[7];

    // workspace layout (~42 MB). aggbuf ALIASES bucket_data (dead after csrB).
    char* ws = (char*)d_ws;
    uint* bucket_data = (uint*)ws;                    // NBKT*BKT_CAP u32 = 16.0 MB
    bf16* aggbuf = (bf16*)ws;                         // N*64 bf16 = 12.8 MB (alias)
    int* csr_src = (int*)(ws + 16015424);             // E i32 = 12.8 MB
    int* row_start = (int*)(ws + 28815424);           // N+1 i32
    int* bucket_cursor = (int*)(ws + 29215488);       // NBKT i32
    int* bucket_base = (int*)(ws + 29217088);         // NBKT i32
    bf16* zbuf = (bf16*)(ws + 29218688);              // N*32 bf16 = 6.4 MB
    bf16* rbuf = (bf16*)(ws + 35618688);              // N*32 bf16 = 6.4 MB
    int* flags = (int*)(ws + 42018688);               // 2 i32

    hipMemsetAsync(bucket_cursor, 0, NBKT * 4, stream);

    detect_kernel<<<1, 64, 0, stream>>>(x, ei, flags);
    scatterA_kernel<<<NBKT, 256, 0, stream>>>(ei, bucket_cursor, bucket_data, flags);
    scanBuckets_kernel<<<1, 512, 0, stream>>>(bucket_cursor, bucket_base);
    csrB_kernel<<<NBKT, 256, 0, stream>>>(bucket_cursor, bucket_base, bucket_data,
                                          csr_src, row_start);
    gather1_kernel<<<6250, 256, 0, stream>>>(x, row_start, csr_src, aggbuf, flags);
    gemm1_kernel<<<1563, 256, 0, stream>>>(x, aggbuf, W1l, b1l, W1r, W2l, b2l,
                                           W2r, zbuf, rbuf, flags);
    node2_kernel<<<8192, 256, 0, stream>>>(row_start, csr_src, zbuf, rbuf, d_out,
                                           flags);
}